// Round 1
// baseline (212.381 us; speedup 1.0000x reference)
//
#include <hip/hip_runtime.h>

#define ALPHA     10.0f
#define INV_BETA  20.0f      // 1/0.05
#define FAR_DELTA 1e10f
#define NSAMP     128        // samples per ray (reference N)
#define TCUT      8.0f       // trans < e^-8 = 3.4e-4 << 1.94e-2 threshold

__device__ __forceinline__ float laplace_density(float sdf) {
    // s = -sdf; s<=0 -> a*0.5*exp(s/b); s>0 -> a*(1-0.5*exp(-s/b))
    float s = -sdf;
    float e = __expf(-fabsf(s) * INV_BETA);
    return (s <= 0.f) ? (0.5f * ALPHA * e) : (ALPHA * (1.f - 0.5f * e));
}

// R10: the rocprof top-5 was ALL fillBufferAligned — our memset — writing
// 396,288 KiB/dispatch = 405.8 MB = 4.000x the 101.4 MB output. out_size is
// BYTES in this harness, so out_size*sizeof(float) over-wrote 4x (~60 us/fill
// at 6.7 TB/s). Fix: delete the memset entirely and fuse the geometry
// zero-fill into the render kernel (3 float4 stores/thread at entry), which
// overlaps the ~96 MB of zero-writes under the kernel's latency-bound
// compute instead of serializing a fill dispatch in front of it.
//
// Render structure unchanged from R9: half-wave (32 lanes) per ray, ray split
// at sample 64; front dist/depth always read; tail + colors predicated on
// transmittance.
__global__ __launch_bounds__(256) void volsdf_render(
    const float* __restrict__ dist,    // [R,128]
    const float* __restrict__ color,   // [R,128,3]
    const float* __restrict__ depth,   // [R,128]
    float*       __restrict__ out,     // [R*3] ray colors, then [R*128*3] geometry
    int R)
{
    // ---- fused geometry zeroing: block b owns rays [8b, 8b+8) ->
    // geometry floats [R*3 + b*3072, +3072) = 768 float4 per block.
    {
        float4* geo = (float4*)(out + (size_t)R * 3);
        const size_t gmax = (size_t)R * 96;          // R*384/4 float4 total
        const float4 z = make_float4(0.f, 0.f, 0.f, 0.f);
        size_t g0 = (size_t)blockIdx.x * 768 + threadIdx.x;
        #pragma unroll
        for (int i = 0; i < 3; ++i) {
            size_t g = g0 + (size_t)i * 256;
            if (g < gmax) geo[g] = z;
        }
    }

    const int lane   = threadIdx.x & 63;
    const int waveId = threadIdx.x >> 6;
    const int sub    = lane & 31;              // sublane within half-wave
    const int half   = lane >> 5;              // which ray of the pair
    const int rayPair = blockIdx.x * 4 + waveId;
    const int ray     = rayPair * 2 + half;
    if (ray >= R) return;                      // wave-uniform for R % 8 == 0

    const size_t rbase = (size_t)ray * NSAMP;

    // ---- front (samples 0..63): 2 samples/lane, 8 B coalesced loads ----
    float2 di = ((const float2*)(dist  + rbase))[sub];
    float2 dp = ((const float2*)(depth + rbase))[sub];

    float nx  = __shfl_down(dp.x, 1, 32);      // depth[2i+2]
    float da  = laplace_density(di.x) * (dp.y - dp.x);
    // sample 63's delta needs depth[64] (tail) — defer; use 0 so w=0 for now.
    float db  = (sub == 31) ? 0.f : laplace_density(di.y) * (nx - dp.y);

    // ---- width-32 exclusive scan of per-lane pair sums (5 steps).
    // Base via shfl_up(incl,1), NOT (incl-local) — R1 cancellation bug.
    float local = da + db;
    float incl  = local;
    #pragma unroll
    for (int off = 1; off < 32; off <<= 1) {
        float v = __shfl_up(incl, off, 32);
        if (sub >= off) incl += v;
    }
    float base = __shfl_up(incl, 1, 32);
    if (sub == 0) base = 0.f;
    float total_lo = __shfl(incl, 31, 32);     // sum d0..d62 (d63 deferred)

    float ar = 0.f, ag = 0.f, ab = 0.f;
    float2 c01, c23, c45;                      // front colors (scope for tail reuse)
    bool haveC = base < TCUT;
    if (haveC) {                               // per-lane exec-masked color load
        const float* cp = color + rbase * 3 + (size_t)sub * 6;
        c01 = ((const float2*)cp)[0];          // r0 g0
        c23 = ((const float2*)cp)[1];          // b0 r1
        c45 = ((const float2*)cp)[2];          // g1 b1
        float wa = (1.f - __expf(-da)) * __expf(-base);
        float wb = (1.f - __expf(-db)) * __expf(-(base + da));  // sub31: 0
        ar = wa * c01.x + wb * c23.y;
        ag = wa * c01.y + wb * c45.x;
        ab = wa * c23.x + wb * c45.y;
    }

    // ---- tail (samples 64..127): only while the ray still transmits ----
    if (total_lo < TCUT) {                     // uniform within the half-wave
        float2 dt = ((const float2*)(dist  + rbase + 64))[sub];
        float2 pt = ((const float2*)(depth + rbase + 64))[sub];

        // exact d63 now that depth[64] is known
        float depth64 = __shfl(pt.x, 0, 32);
        float d63l = laplace_density(di.y) * (depth64 - dp.y); // valid at sub31
        float d63  = __shfl(d63l, 31, 32);
        if (sub == 31 && haveC) {              // sample 63's color contribution
            float w63 = (1.f - __expf(-d63)) * __expf(-(base + da));
            ar += w63 * c23.y; ag += w63 * c45.x; ab += w63 * c45.y;
        }

        float nxt = __shfl_down(pt.x, 1, 32);
        float ea  = laplace_density(dt.x) * (pt.y - pt.x);
        float eb  = laplace_density(dt.y) *
                    ((sub == 31) ? FAR_DELTA : (nxt - pt.y)); // ~1e11, prefix-safe
        float loc2 = ea + eb;
        float inc2 = loc2;
        #pragma unroll
        for (int off = 1; off < 32; off <<= 1) {
            float v = __shfl_up(inc2, off, 32);
            if (sub >= off) inc2 += v;
        }
        float base2 = __shfl_up(inc2, 1, 32);
        if (sub == 0) base2 = 0.f;
        base2 += total_lo + d63;

        if (base2 < TCUT) {                    // per-lane tail color
            const float* cp = color + (rbase + 64) * 3 + (size_t)sub * 6;
            float2 t01 = ((const float2*)cp)[0];
            float2 t23 = ((const float2*)cp)[1];
            float2 t45 = ((const float2*)cp)[2];
            float wa = (1.f - __expf(-ea)) * __expf(-base2);
            float wb = (1.f - __expf(-eb)) * __expf(-(base2 + ea));
            ar += wa * t01.x + wb * t23.y;
            ag += wa * t01.y + wb * t45.x;
            ab += wa * t23.x + wb * t45.y;
        }
    }

    // ---- width-32 reduction (5 steps); sublane 0 of each half holds the sum
    #pragma unroll
    for (int off = 16; off > 0; off >>= 1) {
        ar += __shfl_down(ar, off, 32);
        ag += __shfl_down(ag, off, 32);
        ab += __shfl_down(ab, off, 32);
    }
    if (sub == 0) {
        out[(size_t)ray * 3 + 0] = ar;
        out[(size_t)ray * 3 + 1] = ag;
        out[(size_t)ray * 3 + 2] = ab;
    }
}

extern "C" void kernel_launch(void* const* d_in, const int* in_sizes, int n_in,
                              void* d_out, int out_size, void* d_ws, size_t ws_size,
                              hipStream_t stream) {
    const float* dist  = (const float*)d_in[0];
    const float* color = (const float*)d_in[1];
    const float* depth = (const float*)d_in[2];
    float* out = (float*)d_out;

    const int R = in_sizes[0] / NSAMP;         // 65536
    const int blocks = (R + 7) / 8;            // 8 rays per 256-thread block

    // No memset: the kernel writes every output byte itself (colors for all
    // rays unconditionally + fused geometry zero-fill covering R*384 floats).
    hipLaunchKernelGGL(volsdf_render, dim3(blocks), dim3(256), 0, stream,
                       dist, color, depth, out, R);
}

// Round 2
// 210.312 us; speedup vs baseline: 1.0098x; 1.0098x over previous
//
#include <hip/hip_runtime.h>

#define ALPHA     10.0f
#define INV_BETA  20.0f      // 1/0.05
#define FAR_DELTA 1e10f
#define NSAMP     128        // samples per ray (reference N)
#define TCUT      8.0f       // trans < e^-8 = 3.4e-4; skipped tail weight sum
                             // telescopes to <= e^-8 << 3.9e-3 tolerance

__device__ __forceinline__ float laplace_density(float sdf) {
    // s = -sdf; s<=0 -> a*0.5*exp(s/b); s>0 -> a*(1-0.5*exp(-s/b))
    float s = -sdf;
    float e = __expf(-fabsf(s) * INV_BETA);
    return (s <= 0.f) ? (0.5f * ALPHA * e) : (ALPHA * (1.f - 0.5f * e));
}

// R11: post-mortem of R10 proved the 405.8MB fills are HARNESS poison (they
// survived our memset removal) and out_size is in floats (R9's memset was
// 101.4MB/15.6us; fused zeroing replaced it with ~19us of kernel writes ->
// observed +3.7us). The kernel itself is <62us (never in top-5) vs ~13us of
// logical bytes -> issue/latency-bound. R11 attacks instruction count:
//   - 16 lanes/ray, 4 samples/lane: dist/depth = one float4 each (16B/lane,
//     half the VMEM instructions), colors = 3x float4 (was 3x float2).
//   - scan 5->4 shuffle steps, reduction 15->12 shuffles.
//   - memset restored but geometry-only (96.5MB; color written by kernel).
__global__ __launch_bounds__(256) void volsdf_render(
    const float* __restrict__ dist,    // [R,128]
    const float* __restrict__ color,   // [R,128,3]
    const float* __restrict__ depth,   // [R,128]
    float*       __restrict__ out,     // [R*3] ray colors (geometry memset'd)
    int R)
{
    const int lane   = threadIdx.x & 63;
    const int waveId = threadIdx.x >> 6;
    const int sub    = lane & 15;              // sublane within 16-lane group
    const int grp    = lane >> 4;              // ray within the wave (0..3)
    const int ray    = (blockIdx.x * 4 + waveId) * 4 + grp;
    if (ray >= R) return;                      // wave-uniform for R % 16 == 0

    const size_t rbase = (size_t)ray * NSAMP;

    // ---- front (samples 0..63): 4 samples/lane, 16 B coalesced loads ----
    float4 di = ((const float4*)(dist  + rbase))[sub];
    float4 dp = ((const float4*)(depth + rbase))[sub];

    float nx = __shfl_down(dp.x, 1, 16);       // depth[4*sub+4]
    float d0 = laplace_density(di.x) * (dp.y - dp.x);
    float d1 = laplace_density(di.y) * (dp.z - dp.y);
    float d2 = laplace_density(di.z) * (dp.w - dp.z);
    // sample 63's delta needs depth[64] (tail) — defer; 0 => w3=0 for now.
    float d3 = (sub == 15) ? 0.f : laplace_density(di.w) * (nx - dp.w);

    // ---- width-16 exclusive scan of per-lane 4-sample sums (4 steps).
    // Base via shfl_up(incl,1), NOT (incl-local) — R1 cancellation bug.
    float incl = d0 + d1 + d2 + d3;
    #pragma unroll
    for (int off = 1; off < 16; off <<= 1) {
        float v = __shfl_up(incl, off, 16);
        if (sub >= off) incl += v;
    }
    float base = __shfl_up(incl, 1, 16);
    if (sub == 0) base = 0.f;
    float total_lo = __shfl(incl, 15, 16);     // sum d0..d62 (d63 deferred)

    float ar = 0.f, ag = 0.f, ab = 0.f;
    float4 c0, c1, c2;                         // front colors (kept for tail d63 fix)
    bool haveC = base < TCUT;                  // skipped weights telescope < e^-8
    if (haveC) {                               // per-lane exec-masked color load
        const float4* cp = (const float4*)(color + rbase * 3 + (size_t)sub * 12);
        c0 = cp[0];                            // r0 g0 b0 r1
        c1 = cp[1];                            // g1 b1 r2 g2
        c2 = cp[2];                            // b2 r3 g3 b3
        float t  = __expf(-base);
        float e0 = __expf(-d0), e1 = __expf(-d1);
        float e2 = __expf(-d2), e3 = __expf(-d3);
        float w0 = t * (1.f - e0); t *= e0;
        float w1 = t * (1.f - e1); t *= e1;
        float w2 = t * (1.f - e2); t *= e2;
        float w3 = t * (1.f - e3);             // sub15: e3=1 -> w3=0
        ar = w0 * c0.x + w1 * c0.w + w2 * c1.z + w3 * c2.y;
        ag = w0 * c0.y + w1 * c1.x + w2 * c1.w + w3 * c2.z;
        ab = w0 * c0.z + w1 * c1.y + w2 * c2.x + w3 * c2.w;
    }

    // ---- tail (samples 64..127): only while the ray still transmits ----
    if (total_lo < TCUT) {                     // uniform within the 16-group
        float4 dt = ((const float4*)(dist  + rbase + 64))[sub];
        float4 pt = ((const float4*)(depth + rbase + 64))[sub];

        // exact d63 now that depth[64] is known
        float depth64 = __shfl(pt.x, 0, 16);
        float d63l = laplace_density(di.w) * (depth64 - dp.w); // valid at sub15
        float d63  = __shfl(d63l, 15, 16);
        if (sub == 15 && haveC) {              // sample 63's color contribution
            float w63 = (1.f - __expf(-d63)) * __expf(-(base + d0 + d1 + d2));
            ar += w63 * c2.y; ag += w63 * c2.z; ab += w63 * c2.w;
        }

        float nxt = __shfl_down(pt.x, 1, 16);  // depth[64+4*sub+4]
        float e0 = laplace_density(dt.x) * (pt.y - pt.x);
        float e1 = laplace_density(dt.y) * (pt.z - pt.y);
        float e2 = laplace_density(dt.z) * (pt.w - pt.z);
        float e3 = laplace_density(dt.w) *
                   ((sub == 15) ? FAR_DELTA : (nxt - pt.w)); // ~1e11, prefix-safe
        float inc2 = e0 + e1 + e2 + e3;
        #pragma unroll
        for (int off = 1; off < 16; off <<= 1) {
            float v = __shfl_up(inc2, off, 16);
            if (sub >= off) inc2 += v;
        }
        float base2 = __shfl_up(inc2, 1, 16);
        if (sub == 0) base2 = 0.f;
        base2 += total_lo + d63;

        if (base2 < TCUT) {                    // per-lane tail color
            const float4* cp = (const float4*)(color + (rbase + 64) * 3
                                               + (size_t)sub * 12);
            float4 t0 = cp[0], t1 = cp[1], t2 = cp[2];
            float t  = __expf(-base2);
            float x0 = __expf(-e0), x1 = __expf(-e1);
            float x2 = __expf(-e2), x3 = __expf(-e3); // sub15: x3=0 -> w3=t
            float w0 = t * (1.f - x0); t *= x0;
            float w1 = t * (1.f - x1); t *= x1;
            float w2 = t * (1.f - x2); t *= x2;
            float w3 = t * (1.f - x3);
            ar += w0 * t0.x + w1 * t0.w + w2 * t1.z + w3 * t2.y;
            ag += w0 * t0.y + w1 * t1.x + w2 * t1.w + w3 * t2.z;
            ab += w0 * t0.z + w1 * t1.y + w2 * t2.x + w3 * t2.w;
        }
    }

    // ---- width-16 reduction (4 steps); sublane 0 of each group holds the sum
    #pragma unroll
    for (int off = 8; off > 0; off >>= 1) {
        ar += __shfl_down(ar, off, 16);
        ag += __shfl_down(ag, off, 16);
        ab += __shfl_down(ab, off, 16);
    }
    if (sub == 0) {
        out[(size_t)ray * 3 + 0] = ar;
        out[(size_t)ray * 3 + 1] = ag;
        out[(size_t)ray * 3 + 2] = ab;
    }
}

extern "C" void kernel_launch(void* const* d_in, const int* in_sizes, int n_in,
                              void* d_out, int out_size, void* d_ws, size_t ws_size,
                              hipStream_t stream) {
    const float* dist  = (const float*)d_in[0];
    const float* color = (const float*)d_in[1];
    const float* depth = (const float*)d_in[2];
    float* out = (float*)d_out;

    const int R = in_sizes[0] / NSAMP;         // 65536
    const int blocks = (R + 15) / 16;          // 16 rays per 256-thread block

    // Zero ONLY the geometry region [R*3, R*3 + R*384): 96.5MB at fill speed.
    // Ray colors are written unconditionally by the kernel.
    hipMemsetAsync(out + (size_t)R * 3, 0, (size_t)R * NSAMP * 3 * sizeof(float),
                   stream);

    hipLaunchKernelGGL(volsdf_render, dim3(blocks), dim3(256), 0, stream,
                       dist, color, depth, out, R);
}